// Round 5
// baseline (940.750 us; speedup 1.0000x reference)
//
#include <hip/hip_runtime.h>
#include <cfloat>

// Problem constants (fixed by the reference):
//   inputs  [8,2048,1024] fp32 -> flat [N=16384, H=4, dh=256]
//   codebook[H=4, K=1024, dh=256] fp32
//   out[0] = loss, out[1..] = quantized (16777216 floats)
#define NH    4
#define NK    1024
#define DHD   256
#define NTOK  16384
#define ROWS  (NH * DHD)   // 1024 floats per token row

// Tiling
#define TN 64     // tokens per block
#define TK 128    // codes per K-tile
#define KC 16     // dh chunk staged in LDS
#define APAD 4
#define BPAD 4

// ---------------------------------------------------------------------------
// Kernel 0: per-code squared norms csq[h*NK + k] = sum_d cb[h][k][d]^2
// (used only for the fast candidate-selection pass; refinement recomputes)
// ---------------------------------------------------------------------------
__global__ __launch_bounds__(64) void csq_kernel(const float* __restrict__ cb,
                                                 float* __restrict__ csq) {
    const int code = blockIdx.x;                 // 0 .. NH*NK-1
    const int lane = threadIdx.x;
    const float4 v = *(const float4*)(cb + (size_t)code * DHD + lane * 4);
    float s = v.x * v.x + v.y * v.y + v.z * v.z + v.w * v.w;
#pragma unroll
    for (int off = 32; off > 0; off >>= 1) s += __shfl_down(s, off, 64);
    if (lane == 0) csq[code] = s;
}

// first-index "less" for (value, index) pairs
__device__ __forceinline__ bool lt_vi(float v, int i, float w, int j) {
    return (v < w) || (v == w && i < j);
}

// ---------------------------------------------------------------------------
// Bit-exact replica of numpy's pairwise sum of squares for n=256 contiguous:
// pw(a,256) = fl( pw128(a[0:128]) + pw128(a[128:256]) ), where pw128 uses
// 8 accumulators unrolled-by-8 (r[j] = sum_i a[8i+j]^2 sequentially) and the
// combine tree ((r0+r1)+(r2+r3)) + ((r4+r5)+(r6+r7)). No FMA contraction.
// ---------------------------------------------------------------------------
__device__ __forceinline__ float np_sq_pairwise256(const float* __restrict__ a) {
#pragma clang fp contract(off)
    float tot = 0.f;
#pragma unroll
    for (int blk = 0; blk < 2; ++blk) {
        const float* p = a + blk * 128;
        float r0 = p[0] * p[0], r1 = p[1] * p[1], r2 = p[2] * p[2], r3 = p[3] * p[3];
        float r4 = p[4] * p[4], r5 = p[5] * p[5], r6 = p[6] * p[6], r7 = p[7] * p[7];
        for (int i = 8; i < 128; i += 8) {
            r0 = r0 + p[i + 0] * p[i + 0];
            r1 = r1 + p[i + 1] * p[i + 1];
            r2 = r2 + p[i + 2] * p[i + 2];
            r3 = r3 + p[i + 3] * p[i + 3];
            r4 = r4 + p[i + 4] * p[i + 4];
            r5 = r5 + p[i + 5] * p[i + 5];
            r6 = r6 + p[i + 6] * p[i + 6];
            r7 = r7 + p[i + 7] * p[i + 7];
        }
        const float res = ((r0 + r1) + (r2 + r3)) + ((r4 + r5) + (r6 + r7));
        tot = (blk == 0) ? res : (tot + res);
    }
    return tot;
}

// Bit-exact replica of np.einsum's contiguous two-operand inner loop:
// single accumulator, sequential ascending d, mul then add (no FMA).
__device__ __forceinline__ float np_dot_seq256(const float* __restrict__ a,
                                               const float* __restrict__ b) {
#pragma clang fp contract(off)
    float s = 0.f;
    for (int i = 0; i < 256; ++i) s = s + a[i] * b[i];
    return s;
}

// ---------------------------------------------------------------------------
// Main fused kernel: fp32 distances -> top-2 -> np-bit-exact refine -> gather
// Grid: (NTOK/TN, NH). Block: 256 threads = 16x16 thread grid,
// thread (ty,tx) owns 4 tokens x 8 codes of the TN x TK dot tile.
// ---------------------------------------------------------------------------
__global__ __launch_bounds__(256) void vq_main(const float* __restrict__ x,
                                               const float* __restrict__ cb,
                                               const float* __restrict__ csq,
                                               float* __restrict__ out) {
    __shared__ float As[KC][TN + APAD];   // [dh-chunk][token]
    __shared__ float Bs[KC][TK + BPAD];   // [dh-chunk][code]
    __shared__ float Cs[TK];              // csq tile
    __shared__ int   Cand[TN][2];         // top-2 candidate codes per token
    __shared__ int   SIdx[TN];            // final argmin per token
    __shared__ float WSum[4];             // per-wave loss partials

    const int tid = threadIdx.x;
    const int h   = blockIdx.y;
    const int t0  = blockIdx.x * TN;
    const int ty  = tid >> 4;             // 0..15 -> token group (4 tokens)
    const int tx  = tid & 15;             // 0..15 -> code group (8 codes)

    const float* xh  = x  + (size_t)t0 * ROWS + h * DHD;   // token stride ROWS
    const float* cbh = cb + (size_t)h * NK * DHD;

    // staging assignments
    const int at = tid >> 2;              // token 0..63 (A stage)
    const int ad = (tid & 3) << 2;        // dim offset 0,4,8,12
    const int bc = tid >> 1;              // code 0..127 (B stage)
    const int bd = (tid & 1) << 3;        // dim offset 0,8

    float b1[4], b2[4];
    int   i1[4], i2[4];
#pragma unroll
    for (int r = 0; r < 4; ++r) { b1[r] = FLT_MAX; b2[r] = FLT_MAX; i1[r] = 0; i2[r] = 0; }

    for (int k0 = 0; k0 < NK; k0 += TK) {
        __syncthreads();  // protect Cs/LDS from previous-iteration readers
        if (tid < TK) Cs[tid] = csq[h * NK + k0 + tid];

        float acc[4][8];
#pragma unroll
        for (int r = 0; r < 4; ++r)
#pragma unroll
            for (int c = 0; c < 8; ++c) acc[r][c] = 0.f;

        for (int d0 = 0; d0 < DHD; d0 += KC) {
            __syncthreads();
            {   // Stage A: 64 tokens x 16 dims -> As[kc][token]
                const float4 a = *(const float4*)(xh + (size_t)at * ROWS + d0 + ad);
                As[ad + 0][at] = a.x; As[ad + 1][at] = a.y;
                As[ad + 2][at] = a.z; As[ad + 3][at] = a.w;
            }
            {   // Stage B: 128 codes x 16 dims -> Bs[kc][code]
                const float* bp = cbh + (size_t)(k0 + bc) * DHD + d0 + bd;
                const float4 b0v = *(const float4*)bp;
                const float4 b1v = *(const float4*)(bp + 4);
                Bs[bd + 0][bc] = b0v.x; Bs[bd + 1][bc] = b0v.y;
                Bs[bd + 2][bc] = b0v.z; Bs[bd + 3][bc] = b0v.w;
                Bs[bd + 4][bc] = b1v.x; Bs[bd + 5][bc] = b1v.y;
                Bs[bd + 6][bc] = b1v.z; Bs[bd + 7][bc] = b1v.w;
            }
            __syncthreads();
#pragma unroll
            for (int kc = 0; kc < KC; ++kc) {
                const float4 a  = *(const float4*)&As[kc][ty << 2];
                const float4 p0 = *(const float4*)&Bs[kc][tx << 3];
                const float4 p1 = *(const float4*)&Bs[kc][(tx << 3) + 4];
                const float aa[4] = {a.x, a.y, a.z, a.w};
                const float bb[8] = {p0.x, p0.y, p0.z, p0.w, p1.x, p1.y, p1.z, p1.w};
#pragma unroll
                for (int r = 0; r < 4; ++r)
#pragma unroll
                    for (int c = 0; c < 8; ++c)
                        acc[r][c] = fmaf(aa[r], bb[c], acc[r][c]);
            }
        }
        // fast metric (x_sq constant per token -> dropped) + running top-2
#pragma unroll
        for (int r = 0; r < 4; ++r) {
#pragma unroll
            for (int c = 0; c < 8; ++c) {
                const float dist = Cs[(tx << 3) + c] - 2.f * acc[r][c];
                const int   idx  = k0 + (tx << 3) + c;
                if (dist < b1[r]) { b2[r] = b1[r]; i2[r] = i1[r]; b1[r] = dist; i1[r] = idx; }
                else if (dist < b2[r]) { b2[r] = dist; i2[r] = idx; }
            }
        }
    }

    // Merge top-2 across the 16 tx-threads sharing each token (xor butterfly
    // over bits 0..3 stays inside each 16-lane group of the wave).
#pragma unroll
    for (int r = 0; r < 4; ++r) {
        float v1 = b1[r], v2 = b2[r];
        int   j1 = i1[r], j2 = i2[r];
#pragma unroll
        for (int m = 1; m <= 8; m <<= 1) {
            const float o1 = __shfl_xor(v1, m, 64);
            const int   oj1 = __shfl_xor(j1, m, 64);
            const float o2 = __shfl_xor(v2, m, 64);
            const int   oj2 = __shfl_xor(j2, m, 64);
            if (lt_vi(o1, oj1, v1, j1)) {
                if (lt_vi(v1, j1, o2, oj2)) { v2 = v1; j2 = j1; }
                else                        { v2 = o2; j2 = oj2; }
                v1 = o1; j1 = oj1;
            } else if (lt_vi(o1, oj1, v2, j2)) {
                v2 = o1; j2 = oj1;
            }
        }
        b1[r] = v1; i1[r] = j1; b2[r] = v2; i2[r] = j2;
    }
    if (tx == 0) {
#pragma unroll
        for (int r = 0; r < 4; ++r) {
            Cand[(ty << 2) + r][0] = i1[r];
            Cand[(ty << 2) + r][1] = i2[r];
        }
    }
    __syncthreads();

    // Refinement: bit-exact emulation of the numpy grader for the 2 candidates:
    //   X  = np.sum(x*x)   (pairwise, n=256)
    //   Ck = np.sum(c*c)   (pairwise, n=256)
    //   Dk = np.einsum dot (sequential fp32 mul+add)
    //   dk = fl( fl(X + Ck) - 2*Dk )   (elementwise fp32 chain; 2*Dk exact)
    // argmin with first-occurrence (lower index) on exact fp32 equality.
    if (tid < 2 * TN) {
        const int token = tid >> 1;          // 0..63
        const int cand  = tid & 1;           // 0..1
        const int code  = Cand[token][cand];
        const float* xr = xh + (size_t)token * ROWS;
        const float* cr = cbh + (size_t)code * DHD;
        const float X = np_sq_pairwise256(xr);
        const float C = np_sq_pairwise256(cr);
        const float D = np_dot_seq256(xr, cr);
        float d;
        {
#pragma clang fp contract(off)
            const float t = X + C;
            d = t - 2.0f * D;
        }
        const float od = __shfl_xor(d, 1, 64);   // other candidate's distance
        if (cand == 0) {
            const int jA = code;                 // Cand[token][0]
            const int jB = Cand[token][1];
            const bool pickB = (od < d) || (od == d && jB < jA);
            SIdx[token] = pickB ? jB : jA;
        }
    }
    __syncthreads();

    // Epilogue: gather codebook rows -> out, accumulate (q-x)^2.
    const int wav  = tid >> 6;   // wave 0..3
    const int lane = tid & 63;
    float lacc = 0.f;
    for (int t = wav; t < TN; t += 4) {
        const float* crow = cbh + (size_t)SIdx[t] * DHD;
        const float* xrow = xh + (size_t)t * ROWS;
        float* orow = out + 1 + (size_t)(t0 + t) * ROWS + h * DHD;
#pragma unroll
        for (int i = 0; i < 4; ++i) {
            const int d = lane + (i << 6);
            const float q   = crow[d];
            const float dif = q - xrow[d];
            lacc += dif * dif;
            orow[d] = q;
        }
    }
#pragma unroll
    for (int off = 32; off > 0; off >>= 1) lacc += __shfl_down(lacc, off, 64);
    if (lane == 0) WSum[wav] = lacc;
    __syncthreads();
    if (tid == 0) {
        const float s = WSum[0] + WSum[1] + WSum[2] + WSum[3];
        atomicAdd(out, s * (0.25f / 16777216.f));  // 0.25 * mean
    }
}

extern "C" void kernel_launch(void* const* d_in, const int* in_sizes, int n_in,
                              void* d_out, int out_size, void* d_ws, size_t ws_size,
                              hipStream_t stream) {
    const float* x   = (const float*)d_in[0];   // inputs  [16777216]
    const float* cb  = (const float*)d_in[1];   // codebook [1048576]
    float*       out = (float*)d_out;           // [1 + 16777216]
    float*       csq = (float*)d_ws;            // [4096] scratch

    // out[0] accumulates the loss via atomicAdd -> must start at 0 each call.
    hipMemsetAsync(d_out, 0, sizeof(float), stream);

    csq_kernel<<<NH * NK, 64, 0, stream>>>(cb, csq);

    dim3 grid(NTOK / TN, NH);
    vq_main<<<grid, 256, 0, stream>>>(x, cb, csq, out);
}

// Round 6
// 591.598 us; speedup vs baseline: 1.5902x; 1.5902x over previous
//
#include <hip/hip_runtime.h>
#include <cfloat>

// Problem constants (fixed by the reference):
//   inputs  [8,2048,1024] fp32 -> flat [N=16384, H=4, dh=256]
//   codebook[H=4, K=1024, dh=256] fp32
//   out[0] = loss, out[1..] = quantized (16777216 floats)
#define NH    4
#define NK    1024
#define DHD   256
#define NTOK  16384
#define ROWS  (NH * DHD)   // 1024 floats per token row

// Tiling: 128x128 tile, 16x16 threads, 8x8 per-thread register tile.
#define TN 128    // tokens per block
#define TK 128    // codes per K-tile
#define KC 16     // dh chunk staged in LDS
#define APAD 4
#define BPAD 4

// ---------------------------------------------------------------------------
// Kernel 0: per-code squared norms csq[h*NK + k] = sum_d cb[h][k][d]^2
// (fast candidate pass only; refinement recomputes np-exactly)
// ---------------------------------------------------------------------------
__global__ __launch_bounds__(64) void csq_kernel(const float* __restrict__ cb,
                                                 float* __restrict__ csq) {
    const int code = blockIdx.x;                 // 0 .. NH*NK-1
    const int lane = threadIdx.x;
    const float4 v = *(const float4*)(cb + (size_t)code * DHD + lane * 4);
    float s = v.x * v.x + v.y * v.y + v.z * v.z + v.w * v.w;
#pragma unroll
    for (int off = 32; off > 0; off >>= 1) s += __shfl_down(s, off, 64);
    if (lane == 0) csq[code] = s;
}

// first-index "less" for (value, index) pairs
__device__ __forceinline__ bool lt_vi(float v, int i, float w, int j) {
    return (v < w) || (v == w && i < j);
}

// ---------------------------------------------------------------------------
// Bit-exact replica of numpy's pairwise sum of squares for n=256 (VERIFIED R5).
// unroll_count pragmas control VGPR use only; arithmetic order unchanged.
// ---------------------------------------------------------------------------
__device__ __forceinline__ float np_sq_pairwise256(const float* __restrict__ a) {
#pragma clang fp contract(off)
    float tot = 0.f;
#pragma unroll
    for (int blk = 0; blk < 2; ++blk) {
        const float* p = a + blk * 128;
        float r0 = p[0] * p[0], r1 = p[1] * p[1], r2 = p[2] * p[2], r3 = p[3] * p[3];
        float r4 = p[4] * p[4], r5 = p[5] * p[5], r6 = p[6] * p[6], r7 = p[7] * p[7];
#pragma clang loop unroll_count(2)
        for (int i = 8; i < 128; i += 8) {
            r0 = r0 + p[i + 0] * p[i + 0];
            r1 = r1 + p[i + 1] * p[i + 1];
            r2 = r2 + p[i + 2] * p[i + 2];
            r3 = r3 + p[i + 3] * p[i + 3];
            r4 = r4 + p[i + 4] * p[i + 4];
            r5 = r5 + p[i + 5] * p[i + 5];
            r6 = r6 + p[i + 6] * p[i + 6];
            r7 = r7 + p[i + 7] * p[i + 7];
        }
        const float res = ((r0 + r1) + (r2 + r3)) + ((r4 + r5) + (r6 + r7));
        tot = (blk == 0) ? res : (tot + res);
    }
    return tot;
}

// Bit-exact replica of np.einsum's sequential fp32 mul+add loop (VERIFIED R5).
__device__ __forceinline__ float np_dot_seq256(const float* __restrict__ a,
                                               const float* __restrict__ b) {
#pragma clang fp contract(off)
    float s = 0.f;
#pragma clang loop unroll_count(4)
    for (int i = 0; i < 256; ++i) s = s + a[i] * b[i];
    return s;
}

// ---------------------------------------------------------------------------
// Main fused kernel. Grid: (NTOK/TN, NH), block 256 = 16x16 threads.
// Thread (ty,tx): tokens ty*8..ty*8+7; codes tx*4..+3 and 64+tx*4..+3
// (split-4 mapping -> B ds_read_b128 at 16B stride -> 2-way aliasing = free).
// ---------------------------------------------------------------------------
__global__ __launch_bounds__(256, 2) void vq_main(const float* __restrict__ x,
                                                  const float* __restrict__ cb,
                                                  const float* __restrict__ csq,
                                                  float* __restrict__ out) {
    __shared__ float As[KC][TN + APAD];   // [dh-chunk][token]
    __shared__ float Bs[KC][TK + BPAD];   // [dh-chunk][code]
    __shared__ float Cs[TK];              // csq tile
    __shared__ int   Cand[TN][2];         // top-2 candidate codes per token
    __shared__ int   SIdx[TN];            // final argmin per token
    __shared__ float WSum[4];             // per-wave loss partials

    const int tid = threadIdx.x;
    const int h   = blockIdx.y;
    const int t0  = blockIdx.x * TN;
    const int ty  = tid >> 4;             // 0..15 -> token group (8 tokens)
    const int tx  = tid & 15;             // 0..15 -> code groups (4+4 codes)

    const float* xh  = x  + (size_t)t0 * ROWS + h * DHD;   // token stride ROWS
    const float* cbh = cb + (size_t)h * NK * DHD;

    // staging assignments: thread -> (row tid>>1, dims (tid&1)*8 .. +7)
    const int sr = tid >> 1;              // token/code 0..127
    const int sd = (tid & 1) << 3;        // dim offset 0 or 8

    float b1[8], b2[8];
    int   i1[8], i2[8];
#pragma unroll
    for (int r = 0; r < 8; ++r) { b1[r] = FLT_MAX; b2[r] = FLT_MAX; i1[r] = 0; i2[r] = 0; }

    for (int k0 = 0; k0 < NK; k0 += TK) {
        __syncthreads();  // protect Cs/LDS from previous-iteration readers
        if (tid < TK) Cs[tid] = csq[h * NK + k0 + tid];

        float acc[8][8];
#pragma unroll
        for (int r = 0; r < 8; ++r)
#pragma unroll
            for (int c = 0; c < 8; ++c) acc[r][c] = 0.f;

        for (int d0 = 0; d0 < DHD; d0 += KC) {
            __syncthreads();
            {   // Stage A: 128 tokens x 16 dims -> As[kc][token] (writes 2-way = free)
                const float* ap = xh + (size_t)sr * ROWS + d0 + sd;
                const float4 a0 = *(const float4*)ap;
                const float4 a1 = *(const float4*)(ap + 4);
                As[sd + 0][sr] = a0.x; As[sd + 1][sr] = a0.y;
                As[sd + 2][sr] = a0.z; As[sd + 3][sr] = a0.w;
                As[sd + 4][sr] = a1.x; As[sd + 5][sr] = a1.y;
                As[sd + 6][sr] = a1.z; As[sd + 7][sr] = a1.w;
            }
            {   // Stage B: 128 codes x 16 dims -> Bs[kc][code]
                const float* bp = cbh + (size_t)(k0 + sr) * DHD + d0 + sd;
                const float4 b0v = *(const float4*)bp;
                const float4 b1v = *(const float4*)(bp + 4);
                Bs[sd + 0][sr] = b0v.x; Bs[sd + 1][sr] = b0v.y;
                Bs[sd + 2][sr] = b0v.z; Bs[sd + 3][sr] = b0v.w;
                Bs[sd + 4][sr] = b1v.x; Bs[sd + 5][sr] = b1v.y;
                Bs[sd + 6][sr] = b1v.z; Bs[sd + 7][sr] = b1v.w;
            }
            __syncthreads();
#pragma unroll 4
            for (int kc = 0; kc < KC; ++kc) {
                const float4 a0 = *(const float4*)&As[kc][ty << 3];
                const float4 a1 = *(const float4*)&As[kc][(ty << 3) + 4];
                const float4 p0 = *(const float4*)&Bs[kc][tx << 2];
                const float4 p1 = *(const float4*)&Bs[kc][64 + (tx << 2)];
                const float aa[8] = {a0.x, a0.y, a0.z, a0.w, a1.x, a1.y, a1.z, a1.w};
                const float bb[8] = {p0.x, p0.y, p0.z, p0.w, p1.x, p1.y, p1.z, p1.w};
#pragma unroll
                for (int r = 0; r < 8; ++r)
#pragma unroll
                    for (int c = 0; c < 8; ++c)
                        acc[r][c] = fmaf(aa[r], bb[c], acc[r][c]);
            }
        }
        // fast metric (x_sq constant per token -> dropped) + running top-2
#pragma unroll
        for (int r = 0; r < 8; ++r) {
#pragma unroll
            for (int c = 0; c < 8; ++c) {
                const int cc   = (c < 4) ? ((tx << 2) + c) : (64 + (tx << 2) + c - 4);
                const float dist = Cs[cc] - 2.f * acc[r][c];
                const int   idx  = k0 + cc;
                if (dist < b1[r]) { b2[r] = b1[r]; i2[r] = i1[r]; b1[r] = dist; i1[r] = idx; }
                else if (dist < b2[r]) { b2[r] = dist; i2[r] = idx; }
            }
        }
    }

    // Merge top-2 across the 16 tx-threads sharing each token (xor butterfly
    // over bits 0..3 stays inside each 16-lane group of the wave).
#pragma unroll
    for (int r = 0; r < 8; ++r) {
        float v1 = b1[r], v2 = b2[r];
        int   j1 = i1[r], j2 = i2[r];
#pragma unroll
        for (int m = 1; m <= 8; m <<= 1) {
            const float o1 = __shfl_xor(v1, m, 64);
            const int   oj1 = __shfl_xor(j1, m, 64);
            const float o2 = __shfl_xor(v2, m, 64);
            const int   oj2 = __shfl_xor(j2, m, 64);
            if (lt_vi(o1, oj1, v1, j1)) {
                if (lt_vi(v1, j1, o2, oj2)) { v2 = v1; j2 = j1; }
                else                        { v2 = o2; j2 = oj2; }
                v1 = o1; j1 = oj1;
            } else if (lt_vi(o1, oj1, v2, j2)) {
                v2 = o1; j2 = oj1;
            }
        }
        b1[r] = v1; i1[r] = j1; b2[r] = v2; i2[r] = j2;
    }
    if (tx == 0) {
#pragma unroll
        for (int r = 0; r < 8; ++r) {
            Cand[(ty << 3) + r][0] = i1[r];
            Cand[(ty << 3) + r][1] = i2[r];
        }
    }
    __syncthreads();

    // Refinement: bit-exact numpy emulation (VERIFIED passing in R5):
    //   X=np pairwise sum(x*x), Ck=np pairwise sum(c*c), Dk=np.einsum seq dot,
    //   dk = fl( fl(X+Ck) - 2*Dk ); argmin first-occurrence on fp32 equality.
    {
        const int token = tid >> 1;          // 0..127
        const int cand  = tid & 1;           // 0..1
        const int code  = Cand[token][cand];
        const float* xr = xh + (size_t)token * ROWS;
        const float* cr = cbh + (size_t)code * DHD;
        const float X = np_sq_pairwise256(xr);
        const float C = np_sq_pairwise256(cr);
        const float D = np_dot_seq256(xr, cr);
        float d;
        {
#pragma clang fp contract(off)
            const float t = X + C;
            d = t - 2.0f * D;
        }
        const float od = __shfl_xor(d, 1, 64);   // other candidate's distance
        if (cand == 0) {
            const int jA = code;                 // Cand[token][0]
            const int jB = Cand[token][1];
            const bool pickB = (od < d) || (od == d && jB < jA);
            SIdx[token] = pickB ? jB : jA;
        }
    }
    __syncthreads();

    // Epilogue: gather codebook rows -> out (float4), accumulate (q-x)^2.
    const int wav  = tid >> 6;   // wave 0..3
    const int lane = tid & 63;
    float lacc = 0.f;
    for (int t = wav; t < TN; t += 4) {
        const float4 q4 = *(const float4*)(cbh + (size_t)SIdx[t] * DHD + (lane << 2));
        const float4 x4 = *(const float4*)(xh + (size_t)t * ROWS + (lane << 2));
        const float dx = q4.x - x4.x, dy = q4.y - x4.y;
        const float dz = q4.z - x4.z, dw = q4.w - x4.w;
        lacc += dx * dx + dy * dy + dz * dz + dw * dw;
        *(float4*)(out + 1 + (size_t)(t0 + t) * ROWS + h * DHD + (lane << 2)) = q4;
    }
#pragma unroll
    for (int off = 32; off > 0; off >>= 1) lacc += __shfl_down(lacc, off, 64);
    if (lane == 0) WSum[wav] = lacc;
    __syncthreads();
    if (tid == 0) {
        const float s = WSum[0] + WSum[1] + WSum[2] + WSum[3];
        atomicAdd(out, s * (0.25f / 16777216.f));  // 0.25 * mean
    }
}

extern "C" void kernel_launch(void* const* d_in, const int* in_sizes, int n_in,
                              void* d_out, int out_size, void* d_ws, size_t ws_size,
                              hipStream_t stream) {
    const float* x   = (const float*)d_in[0];   // inputs  [16777216]
    const float* cb  = (const float*)d_in[1];   // codebook [1048576]
    float*       out = (float*)d_out;           // [1 + 16777216]
    float*       csq = (float*)d_ws;            // [4096] scratch

    // out[0] accumulates the loss via atomicAdd -> must start at 0 each call.
    hipMemsetAsync(d_out, 0, sizeof(float), stream);

    csq_kernel<<<NH * NK, 64, 0, stream>>>(cb, csq);

    dim3 grid(NTOK / TN, NH);
    vq_main<<<grid, 256, 0, stream>>>(x, cb, csq, out);
}

// Round 7
// 466.371 us; speedup vs baseline: 2.0172x; 1.2685x over previous
//
#include <hip/hip_runtime.h>
#include <cfloat>

// Problem constants (fixed by the reference):
//   inputs  [8,2048,1024] fp32 -> flat [N=16384, H=4, dh=256]
//   codebook[H=4, K=1024, dh=256] fp32
//   out[0] = loss, out[1..] = quantized (16777216 floats)
#define NH    4
#define NK    1024
#define DHD   256
#define NTOK  16384
#define ROWS  (NH * DHD)   // 1024 floats per token row

typedef __attribute__((ext_vector_type(8))) short bf16x8;
typedef __attribute__((ext_vector_type(4))) float f32x4;

// ---------------------------------------------------------------------------
// Workspace layout (bytes). Fast path needs ~68 MB; else fp32 fallback.
// ---------------------------------------------------------------------------
#define WS_CSQ  ((size_t)0)
#define WS_BH   ((size_t)16384)                    // cb hi: 4*8*4*1024*16 = 2 MB
#define WS_BL   (WS_BH + (size_t)2097152)          // cb lo: 2 MB
#define WS_AH   (WS_BL + (size_t)2097152)          // x hi: 4*8*4*16384*16 = 32 MB
#define WS_AL   (WS_AH + (size_t)33554432)         // x lo: 32 MB
#define WS_NEED (WS_AL + (size_t)33554432)

// ---------------------------------------------------------------------------
// bf16 split helpers (round-to-nearest-even)
// ---------------------------------------------------------------------------
__device__ __forceinline__ unsigned short f32_to_bf16_rn(float f) {
    unsigned u = __float_as_uint(f);
    u += 0x7FFFu + ((u >> 16) & 1u);
    return (unsigned short)(u >> 16);
}
__device__ __forceinline__ float bf16_as_f32(unsigned short h) {
    return __uint_as_float(((unsigned)h) << 16);
}

// ---------------------------------------------------------------------------
// Kernel 0: per-code squared norms csq[h*NK + k] = sum_d cb[h][k][d]^2 (fp32)
// ---------------------------------------------------------------------------
__global__ __launch_bounds__(64) void csq_kernel(const float* __restrict__ cb,
                                                 float* __restrict__ csq) {
    const int code = blockIdx.x;                 // 0 .. NH*NK-1
    const int lane = threadIdx.x;
    const float4 v = *(const float4*)(cb + (size_t)code * DHD + lane * 4);
    float s = v.x * v.x + v.y * v.y + v.z * v.z + v.w * v.w;
#pragma unroll
    for (int off = 32; off > 0; off >>= 1) s += __shfl_down(s, off, 64);
    if (lane == 0) csq[code] = s;
}

// ---------------------------------------------------------------------------
// cvt_x: x fp32 -> hi/lo bf16, pre-swizzled [h][dc(8)][kk(4)][token] 16B units
// Block 128 threads = 1 token (coalesced 4KB read).
// ---------------------------------------------------------------------------
__global__ __launch_bounds__(128) void cvt_x_kernel(const float* __restrict__ x,
                                                    uint4* __restrict__ axh,
                                                    uint4* __restrict__ axl) {
    const int t = blockIdx.x;
    const int u = threadIdx.x;                   // 0..127 (dh-octet in token row)
    const float* src = x + (size_t)t * ROWS + u * 8;
    unsigned wh[4], wl[4];
#pragma unroll
    for (int i = 0; i < 4; ++i) {
        const float f0 = src[2 * i], f1 = src[2 * i + 1];
        const unsigned short h0 = f32_to_bf16_rn(f0);
        const unsigned short h1 = f32_to_bf16_rn(f1);
        const unsigned short l0 = f32_to_bf16_rn(f0 - bf16_as_f32(h0));
        const unsigned short l1 = f32_to_bf16_rn(f1 - bf16_as_f32(h1));
        wh[i] = (unsigned)h0 | ((unsigned)h1 << 16);
        wl[i] = (unsigned)l0 | ((unsigned)l1 << 16);
    }
    const int hh = u >> 5, dc = (u >> 2) & 7, kk = u & 3;
    const size_t unit = (size_t)((hh * 8 + dc) * 4 + kk) * NTOK + t;
    axh[unit] = make_uint4(wh[0], wh[1], wh[2], wh[3]);
    axl[unit] = make_uint4(wl[0], wl[1], wl[2], wl[3]);
}

// ---------------------------------------------------------------------------
// cvt_cb: codebook fp32 -> hi/lo bf16, swizzled [h][dc][kk][code] 16B units
// Block 256 threads = 8 codes.
// ---------------------------------------------------------------------------
__global__ __launch_bounds__(256) void cvt_cb_kernel(const float* __restrict__ cb,
                                                     uint4* __restrict__ bch,
                                                     uint4* __restrict__ bcl) {
    const int g = blockIdx.x * 8 + (threadIdx.x >> 5);   // 0..4095
    const int o = threadIdx.x & 31;                      // dh-octet
    const float* src = cb + (size_t)g * DHD + o * 8;
    unsigned wh[4], wl[4];
#pragma unroll
    for (int i = 0; i < 4; ++i) {
        const float f0 = src[2 * i], f1 = src[2 * i + 1];
        const unsigned short h0 = f32_to_bf16_rn(f0);
        const unsigned short h1 = f32_to_bf16_rn(f1);
        const unsigned short l0 = f32_to_bf16_rn(f0 - bf16_as_f32(h0));
        const unsigned short l1 = f32_to_bf16_rn(f1 - bf16_as_f32(h1));
        wh[i] = (unsigned)h0 | ((unsigned)h1 << 16);
        wl[i] = (unsigned)l0 | ((unsigned)l1 << 16);
    }
    const int hh = g >> 10, c = g & 1023, dc = o >> 2, kk = o & 3;
    const size_t unit = (size_t)((hh * 8 + dc) * 4 + kk) * NK + c;
    bch[unit] = make_uint4(wh[0], wh[1], wh[2], wh[3]);
    bcl[unit] = make_uint4(wl[0], wl[1], wl[2], wl[3]);
}

// first-index "less" for (value, index) pairs
__device__ __forceinline__ bool lt_vi(float v, int i, float w, int j) {
    return (v < w) || (v == w && i < j);
}

// ---------------------------------------------------------------------------
// Bit-exact replica of numpy's pairwise sum of squares for n=256 (VERIFIED R5)
// ---------------------------------------------------------------------------
__device__ __forceinline__ float np_sq_pairwise256(const float* __restrict__ a) {
#pragma clang fp contract(off)
    float tot = 0.f;
#pragma unroll
    for (int blk = 0; blk < 2; ++blk) {
        const float* p = a + blk * 128;
        float r0 = p[0] * p[0], r1 = p[1] * p[1], r2 = p[2] * p[2], r3 = p[3] * p[3];
        float r4 = p[4] * p[4], r5 = p[5] * p[5], r6 = p[6] * p[6], r7 = p[7] * p[7];
#pragma clang loop unroll_count(2)
        for (int i = 8; i < 128; i += 8) {
            r0 = r0 + p[i + 0] * p[i + 0];
            r1 = r1 + p[i + 1] * p[i + 1];
            r2 = r2 + p[i + 2] * p[i + 2];
            r3 = r3 + p[i + 3] * p[i + 3];
            r4 = r4 + p[i + 4] * p[i + 4];
            r5 = r5 + p[i + 5] * p[i + 5];
            r6 = r6 + p[i + 6] * p[i + 6];
            r7 = r7 + p[i + 7] * p[i + 7];
        }
        const float res = ((r0 + r1) + (r2 + r3)) + ((r4 + r5) + (r6 + r7));
        tot = (blk == 0) ? res : (tot + res);
    }
    return tot;
}

// Bit-exact replica of np.einsum's sequential fp32 mul+add loop (VERIFIED R5).
__device__ __forceinline__ float np_dot_seq256(const float* __restrict__ a,
                                               const float* __restrict__ b) {
#pragma clang fp contract(off)
    float s = 0.f;
#pragma clang loop unroll_count(4)
    for (int i = 0; i < 256; ++i) s = s + a[i] * b[i];
    return s;
}

// ===========================================================================
// FAST PATH: split-bf16 MFMA kernel.
// Grid (NTOK/128, NH), 256 threads / 4 waves. Wave w: tokens w*32..w*32+31
// (2 MFMA row-tiles of 16). Codes looped in 64-wide tiles (4 col-tiles).
// dot = hi*hi + hi*lo + lo*hi via mfma_f32_16x16x32_bf16; A token-stationary
// in registers; B staged in LDS per 64-code tile.
// Layouts (doc-verified): A-frag A[m=lane&15][k=(lane>>4)*8+j];
// B-frag (B^T input [code][dh]): B[n=lane&15][k=(lane>>4)*8+j];
// C/D: col(n)=lane&15, row(m)=(lane>>4)*4+reg.
// ===========================================================================
__global__ __launch_bounds__(256, 2) void vq_mfma(const float* __restrict__ x,
                                                  const float* __restrict__ cb,
                                                  const float* __restrict__ csq,
                                                  const uint4* __restrict__ axh,
                                                  const uint4* __restrict__ axl,
                                                  const uint4* __restrict__ bch,
                                                  const uint4* __restrict__ bcl,
                                                  float* __restrict__ out) {
    __shared__ uint4 BsH[2048];    // 64 codes x 256 dh (hi) as [dcKK(32)][code(64)]
    __shared__ uint4 BsL[2048];    // lo
    __shared__ float Cs[64];
    __shared__ int   Cand[128][2];
    __shared__ int   SIdx[128];
    __shared__ float WSum[4];

    const int tid  = threadIdx.x;
    const int h    = blockIdx.y;
    const int t0   = blockIdx.x * 128;
    const int wv   = tid >> 6;
    const int lane = tid & 63;
    const int kk   = lane >> 4;    // 0..3 (k-octet)
    const int ln   = lane & 15;

    const float* xh  = x  + (size_t)t0 * ROWS + h * DHD;
    const float* cbh = cb + (size_t)h * NK * DHD;

    // A fragments: token-stationary, whole dh in registers (hi+lo).
    bf16x8 aH[2][8], aL[2][8];
    {
        const int tokb = t0 + wv * 32 + ln;
#pragma unroll
        for (int rt = 0; rt < 2; ++rt)
#pragma unroll
            for (int dc = 0; dc < 8; ++dc) {
                const size_t u = (size_t)((h * 8 + dc) * 4 + kk) * NTOK + tokb + rt * 16;
                aH[rt][dc] = *(const bf16x8*)&axh[u];
                aL[rt][dc] = *(const bf16x8*)&axl[u];
            }
    }

    float b1[8], b2[8];
    int   i1[8], i2[8];
#pragma unroll
    for (int s = 0; s < 8; ++s) { b1[s] = FLT_MAX; b2[s] = FLT_MAX; i1[s] = 0; i2[s] = 0; }

    for (int k0 = 0; k0 < NK; k0 += 64) {
        __syncthreads();  // protect Bs/Cs from previous-iteration readers
        // stage B tile: 2048 hi + 2048 lo units; LDS idx == local unit idx.
#pragma unroll
        for (int p = 0; p < 8; ++p) {
            const int i = p * 256 + tid;          // 0..2047
            const int dcKK = i >> 6, c = i & 63;
            const size_t w = (size_t)(h * 32 + dcKK) * NK + k0 + c;
            BsH[i] = bch[w];
            BsL[i] = bcl[w];
        }
        if (tid < 64) Cs[tid] = csq[h * NK + k0 + tid];
        __syncthreads();

        f32x4 acc[2][4];
#pragma unroll
        for (int rt = 0; rt < 2; ++rt)
#pragma unroll
            for (int ct = 0; ct < 4; ++ct) acc[rt][ct] = (f32x4){0.f, 0.f, 0.f, 0.f};

#pragma unroll
        for (int dc = 0; dc < 8; ++dc) {
#pragma unroll
            for (int ct = 0; ct < 4; ++ct) {
                const int bu = (dc * 4 + kk) * 64 + ct * 16 + ln;
                const bf16x8 bH = *(const bf16x8*)&BsH[bu];
                const bf16x8 bL = *(const bf16x8*)&BsL[bu];
#pragma unroll
                for (int rt = 0; rt < 2; ++rt) {
                    acc[rt][ct] = __builtin_amdgcn_mfma_f32_16x16x32_bf16(aH[rt][dc], bH, acc[rt][ct], 0, 0, 0);
                    acc[rt][ct] = __builtin_amdgcn_mfma_f32_16x16x32_bf16(aH[rt][dc], bL, acc[rt][ct], 0, 0, 0);
                    acc[rt][ct] = __builtin_amdgcn_mfma_f32_16x16x32_bf16(aL[rt][dc], bH, acc[rt][ct], 0, 0, 0);
                }
            }
        }

        // distances (x_sq dropped: per-token constant) + running top-2
#pragma unroll
        for (int rt = 0; rt < 2; ++rt)
#pragma unroll
            for (int ct = 0; ct < 4; ++ct) {
                const float cs   = Cs[ct * 16 + ln];
                const int   codg = k0 + ct * 16 + ln;
#pragma unroll
                for (int r = 0; r < 4; ++r) {
                    const float dist = cs - 2.f * acc[rt][ct][r];
                    const int   s    = rt * 4 + r;
                    if (dist < b1[s]) { b2[s] = b1[s]; i2[s] = i1[s]; b1[s] = dist; i1[s] = codg; }
                    else if (dist < b2[s]) { b2[s] = dist; i2[s] = codg; }
                }
            }
    }

    // Merge top-2 across the 16 lanes sharing each token (xor bits 0..3).
#pragma unroll
    for (int s = 0; s < 8; ++s) {
        float v1 = b1[s], v2 = b2[s];
        int   j1 = i1[s], j2 = i2[s];
#pragma unroll
        for (int m = 1; m <= 8; m <<= 1) {
            const float o1 = __shfl_xor(v1, m, 64);
            const int   oj1 = __shfl_xor(j1, m, 64);
            const float o2 = __shfl_xor(v2, m, 64);
            const int   oj2 = __shfl_xor(j2, m, 64);
            if (lt_vi(o1, oj1, v1, j1)) {
                if (lt_vi(v1, j1, o2, oj2)) { v2 = v1; j2 = j1; }
                else                        { v2 = o2; j2 = oj2; }
                v1 = o1; j1 = oj1;
            } else if (lt_vi(o1, oj1, v2, j2)) {
                v2 = o1; j2 = oj1;
            }
        }
        if (ln == 0) {
            const int tl = wv * 32 + (s >> 2) * 16 + kk * 4 + (s & 3);
            Cand[tl][0] = j1;
            Cand[tl][1] = j2;
        }
    }
    __syncthreads();

    // Refinement: bit-exact numpy emulation on 2 candidates (VERIFIED R5/R6).
    {
        const int token = tid >> 1;          // 0..127
        const int cand  = tid & 1;
        const int code  = Cand[token][cand];
        const float* xr = xh + (size_t)token * ROWS;
        const float* cr = cbh + (size_t)code * DHD;
        const float X = np_sq_pairwise256(xr);
        const float C = np_sq_pairwise256(cr);
        const float D = np_dot_seq256(xr, cr);
        float d;
        {
#pragma clang fp contract(off)
            const float t = X + C;
            d = t - 2.0f * D;
        }
        const float od = __shfl_xor(d, 1, 64);
        if (cand == 0) {
            const int jA = code;
            const int jB = Cand[token][1];
            const bool pickB = (od < d) || (od == d && jB < jA);
            SIdx[token] = pickB ? jB : jA;
        }
    }
    __syncthreads();

    // Epilogue: gather codebook rows -> out (float4), accumulate (q-x)^2.
    float lacc = 0.f;
    for (int t = wv; t < 128; t += 4) {
        const float4 q4 = *(const float4*)(cbh + (size_t)SIdx[t] * DHD + (lane << 2));
        const float4 x4 = *(const float4*)(xh + (size_t)t * ROWS + (lane << 2));
        const float dx = q4.x - x4.x, dy = q4.y - x4.y;
        const float dz = q4.z - x4.z, dw = q4.w - x4.w;
        lacc += dx * dx + dy * dy + dz * dz + dw * dw;
        *(float4*)(out + 1 + (size_t)(t0 + t) * ROWS + h * DHD + (lane << 2)) = q4;
    }
#pragma unroll
    for (int off = 32; off > 0; off >>= 1) lacc += __shfl_down(lacc, off, 64);
    if (lane == 0) WSum[wv] = lacc;
    __syncthreads();
    if (tid == 0) {
        const float s = WSum[0] + WSum[1] + WSum[2] + WSum[3];
        atomicAdd(out, s * (0.25f / 16777216.f));  // 0.25 * mean
    }
}

// ===========================================================================
// FALLBACK (ws too small): R6 fp32 kernel — verified passing at 558 us.
// ===========================================================================
#define TN 128
#define TK 128
#define KC 16
#define APAD 4
#define BPAD 4

__global__ __launch_bounds__(256, 2) void vq_main_fp32(const float* __restrict__ x,
                                                       const float* __restrict__ cb,
                                                       const float* __restrict__ csq,
                                                       float* __restrict__ out) {
    __shared__ float As[KC][TN + APAD];
    __shared__ float Bs[KC][TK + BPAD];
    __shared__ float Cs[TK];
    __shared__ int   Cand[TN][2];
    __shared__ int   SIdx[TN];
    __shared__ float WSum[4];

    const int tid = threadIdx.x;
    const int h   = blockIdx.y;
    const int t0  = blockIdx.x * TN;
    const int ty  = tid >> 4;
    const int tx  = tid & 15;

    const float* xh  = x  + (size_t)t0 * ROWS + h * DHD;
    const float* cbh = cb + (size_t)h * NK * DHD;

    const int sr = tid >> 1;
    const int sd = (tid & 1) << 3;

    float b1[8], b2[8];
    int   i1[8], i2[8];
#pragma unroll
    for (int r = 0; r < 8; ++r) { b1[r] = FLT_MAX; b2[r] = FLT_MAX; i1[r] = 0; i2[r] = 0; }

    for (int k0 = 0; k0 < NK; k0 += TK) {
        __syncthreads();
        if (tid < TK) Cs[tid] = csq[h * NK + k0 + tid];

        float acc[8][8];
#pragma unroll
        for (int r = 0; r < 8; ++r)
#pragma unroll
            for (int c = 0; c < 8; ++c) acc[r][c] = 0.f;

        for (int d0 = 0; d0 < DHD; d0 += KC) {
            __syncthreads();
            {
                const float* ap = xh + (size_t)sr * ROWS + d0 + sd;
                const float4 a0 = *(const float4*)ap;
                const float4 a1 = *(const float4*)(ap + 4);
                As[sd + 0][sr] = a0.x; As[sd + 1][sr] = a0.y;
                As[sd + 2][sr] = a0.z; As[sd + 3][sr] = a0.w;
                As[sd + 4][sr] = a1.x; As[sd + 5][sr] = a1.y;
                As[sd + 6][sr] = a1.z; As[sd + 7][sr] = a1.w;
            }
            {
                const float* bp = cbh + (size_t)(k0 + sr) * DHD + d0 + sd;
                const float4 b0v = *(const float4*)bp;
                const float4 b1v = *(const float4*)(bp + 4);
                Bs[sd + 0][sr] = b0v.x; Bs[sd + 1][sr] = b0v.y;
                Bs[sd + 2][sr] = b0v.z; Bs[sd + 3][sr] = b0v.w;
                Bs[sd + 4][sr] = b1v.x; Bs[sd + 5][sr] = b1v.y;
                Bs[sd + 6][sr] = b1v.z; Bs[sd + 7][sr] = b1v.w;
            }
            __syncthreads();
#pragma unroll 4
            for (int kc = 0; kc < KC; ++kc) {
                const float4 a0 = *(const float4*)&As[kc][ty << 3];
                const float4 a1 = *(const float4*)&As[kc][(ty << 3) + 4];
                const float4 p0 = *(const float4*)&Bs[kc][tx << 2];
                const float4 p1 = *(const float4*)&Bs[kc][64 + (tx << 2)];
                const float aa[8] = {a0.x, a0.y, a0.z, a0.w, a1.x, a1.y, a1.z, a1.w};
                const float bb[8] = {p0.x, p0.y, p0.z, p0.w, p1.x, p1.y, p1.z, p1.w};
#pragma unroll
                for (int r = 0; r < 8; ++r)
#pragma unroll
                    for (int c = 0; c < 8; ++c)
                        acc[r][c] = fmaf(aa[r], bb[c], acc[r][c]);
            }
        }
#pragma unroll
        for (int r = 0; r < 8; ++r) {
#pragma unroll
            for (int c = 0; c < 8; ++c) {
                const int cc = (c < 4) ? ((tx << 2) + c) : (64 + (tx << 2) + c - 4);
                const float dist = Cs[cc] - 2.f * acc[r][c];
                const int   idx  = k0 + cc;
                if (dist < b1[r]) { b2[r] = b1[r]; i2[r] = i1[r]; b1[r] = dist; i1[r] = idx; }
                else if (dist < b2[r]) { b2[r] = dist; i2[r] = idx; }
            }
        }
    }

#pragma unroll
    for (int r = 0; r < 8; ++r) {
        float v1 = b1[r], v2 = b2[r];
        int   j1 = i1[r], j2 = i2[r];
#pragma unroll
        for (int m = 1; m <= 8; m <<= 1) {
            const float o1 = __shfl_xor(v1, m, 64);
            const int   oj1 = __shfl_xor(j1, m, 64);
            const float o2 = __shfl_xor(v2, m, 64);
            const int   oj2 = __shfl_xor(j2, m, 64);
            if (lt_vi(o1, oj1, v1, j1)) {
                if (lt_vi(v1, j1, o2, oj2)) { v2 = v1; j2 = j1; }
                else                        { v2 = o2; j2 = oj2; }
                v1 = o1; j1 = oj1;
            } else if (lt_vi(o1, oj1, v2, j2)) {
                v2 = o1; j2 = oj1;
            }
        }
        b1[r] = v1; i1[r] = j1; b2[r] = v2; i2[r] = j2;
    }
    if (tx == 0) {
#pragma unroll
        for (int r = 0; r < 8; ++r) {
            Cand[(ty << 3) + r][0] = i1[r];
            Cand[(ty << 3) + r][1] = i2[r];
        }
    }
    __syncthreads();

    {
        const int token = tid >> 1;
        const int cand  = tid & 1;
        const int code  = Cand[token][cand];
        const float* xr = xh + (size_t)token * ROWS;
        const float* cr = cbh + (size_t)code * DHD;
        const float X = np_sq_pairwise256(xr);
        const float C = np_sq_pairwise256(cr);
        const float D = np_dot_seq256(xr, cr);
        float d;
        {
#pragma clang fp contract(off)
            const float t = X + C;
            d = t - 2.0f * D;
        }
        const float od = __shfl_xor(d, 1, 64);
        if (cand == 0) {
            const int jA = code;
            const int jB = Cand[token][1];
            const bool pickB = (od < d) || (od == d && jB < jA);
            SIdx[token] = pickB ? jB : jA;
        }
    }
    __syncthreads();

    const int wav  = tid >> 6;
    const int lane = tid & 63;
    float lacc = 0.f;
    for (int t = wav; t < TN; t += 4) {
        const float4 q4 = *(const float4*)(cbh + (size_t)SIdx[t] * DHD + (lane << 2));
        const float4 x4 = *(const float4*)(xh + (size_t)t * ROWS + (lane << 2));
        const float dx = q4.x - x4.x, dy = q4.y - x4.y;
        const float dz = q4.z - x4.z, dw = q4.w - x4.w;
        lacc += dx * dx + dy * dy + dz * dz + dw * dw;
        *(float4*)(out + 1 + (size_t)(t0 + t) * ROWS + h * DHD + (lane << 2)) = q4;
    }
#pragma unroll
    for (int off = 32; off > 0; off >>= 1) lacc += __shfl_down(lacc, off, 64);
    if (lane == 0) WSum[wav] = lacc;
    __syncthreads();
    if (tid == 0) {
        const float s = WSum[0] + WSum[1] + WSum[2] + WSum[3];
        atomicAdd(out, s * (0.25f / 16777216.f));
    }
}

extern "C" void kernel_launch(void* const* d_in, const int* in_sizes, int n_in,
                              void* d_out, int out_size, void* d_ws, size_t ws_size,
                              hipStream_t stream) {
    const float* x   = (const float*)d_in[0];   // inputs  [16777216]
    const float* cb  = (const float*)d_in[1];   // codebook [1048576]
    float*       out = (float*)d_out;           // [1 + 16777216]
    char*        ws  = (char*)d_ws;
    float*       csq = (float*)(ws + WS_CSQ);

    hipMemsetAsync(d_out, 0, sizeof(float), stream);
    csq_kernel<<<NH * NK, 64, 0, stream>>>(cb, csq);

    if (ws_size >= WS_NEED) {
        uint4* bch = (uint4*)(ws + WS_BH);
        uint4* bcl = (uint4*)(ws + WS_BL);
        uint4* axh = (uint4*)(ws + WS_AH);
        uint4* axl = (uint4*)(ws + WS_AL);
        cvt_cb_kernel<<<NH * NK / 8, 256, 0, stream>>>(cb, bch, bcl);
        cvt_x_kernel<<<NTOK, 128, 0, stream>>>(x, axh, axl);
        dim3 grid(NTOK / 128, NH);
        vq_mfma<<<grid, 256, 0, stream>>>(x, cb, csq, axh, axl, bch, bcl, out);
    } else {
        dim3 grid(NTOK / TN, NH);
        vq_main_fp32<<<grid, 256, 0, stream>>>(x, cb, csq, out);
    }
}